// Round 1
// baseline (413.856 us; speedup 1.0000x reference)
//
#include <hip/hip_runtime.h>

// Lyapunov spectrum via chunked QR scan with warm-up re-convergence.
// inp: (T=4096, 9, B=2048) fp32.  out: (3, B) fp32.
// R4: 1 batch/thread (scalar f32, dword loads), NCHUNK=64, WARM=32, PF=4 ring.
//     131072 threads = 2048 waves = 2 waves/SIMD (vs 1 in R3): doubles
//     latency-hiding at IDENTICAL HBM traffic (~460 MB, 1.5x amplification).
//     Per-wave load is 64 lanes x 4B = 256B, fully coalesced.

constexpr int T_STEPS = 4096;
constexpr int BATCH   = 2048;
constexpr int NCHUNK  = 64;
constexpr int KSEG    = T_STEPS / NCHUNK;  // 64
constexpr int WARM    = 32;                // gap ~0.31/step -> e^-10 seam error
constexpr int PF      = 4;                 // prefetch ring depth (divides WARM and KSEG)

constexpr int ROW = 9 * BATCH;             // floats per time step (18432)
constexpr int COL = BATCH;                 // floats per m column (2048)

__device__ __forceinline__ void lya_step(const float J[9], float Q[9], float d[3]) {
    // M = J * Q  (3x3 per thread, one batch)
    float M[9];
#pragma unroll
    for (int i = 0; i < 3; ++i) {
#pragma unroll
        for (int j = 0; j < 3; ++j) {
            M[i * 3 + j] = J[i * 3 + 0] * Q[0 * 3 + j]
                         + J[i * 3 + 1] * Q[1 * 3 + j]
                         + J[i * 3 + 2] * Q[2 * 3 + j];
        }
    }
    // Classical Gram-Schmidt (projections vs original cols), 1/d = rsq^2
    float b0x = M[0], b0y = M[3], b0z = M[6];
    float d00 = b0x * b0x + b0y * b0y + b0z * b0z;
    float r0 = __builtin_amdgcn_rsqf(d00);
    float inv00 = r0 * r0;

    float x1x = M[1], x1y = M[4], x1z = M[7];
    float c01 = (b0x * x1x + b0y * x1y + b0z * x1z) * inv00;
    float b1x = x1x - c01 * b0x;
    float b1y = x1y - c01 * b0y;
    float b1z = x1z - c01 * b0z;
    float d11 = b1x * b1x + b1y * b1y + b1z * b1z;
    float r1 = __builtin_amdgcn_rsqf(d11);
    float inv11 = r1 * r1;

    float x2x = M[2], x2y = M[5], x2z = M[8];
    float c02 = (b0x * x2x + b0y * x2y + b0z * x2z) * inv00;
    float c12 = (b1x * x2x + b1y * x2y + b1z * x2z) * inv11;
    float b2x = x2x - c02 * b0x - c12 * b1x;
    float b2y = x2y - c02 * b0y - c12 * b1y;
    float b2z = x2z - c02 * b0z - c12 * b1z;
    float d22 = b2x * b2x + b2y * b2y + b2z * b2z;
    float r2 = __builtin_amdgcn_rsqf(d22);

    Q[0] = b0x * r0; Q[3] = b0y * r0; Q[6] = b0z * r0;
    Q[1] = b1x * r1; Q[4] = b1y * r1; Q[7] = b1z * r1;
    Q[2] = b2x * r2; Q[5] = b2y * r2; Q[8] = b2z * r2;
    d[0] = d00; d[1] = d11; d[2] = d22;
}

__global__ __launch_bounds__(256) void lya_kernel(const float* __restrict__ inp,
                                                  float* __restrict__ out) {
    const int tid   = blockIdx.x * 256 + threadIdx.x;
    const int l     = tid & (BATCH - 1);   // batch index
    const int chunk = tid >> 11;           // block-uniform (2048 threads/chunk)
    const int kacc  = chunk * KSEG;
    const int s0    = (kacc >= WARM) ? (kacc - WARM) : 0;
    const int nwarm = kacc - s0;           // 0 (chunk 0) or WARM

    float Q[9] = {1.f, 0.f, 0.f,
                  0.f, 1.f, 0.f,
                  0.f, 0.f, 1.f};
    float acc0 = 0.f, acc1 = 0.f, acc2 = 0.f;

    // Preload PF-deep ring: steps s0 .. s0+PF-1 (s0+PF-1 <= 4000+3 < 4096).
    float Jb[PF][9];
#pragma unroll
    for (int r = 0; r < PF; ++r) {
        const float* p = inp + (size_t)(s0 + r) * ROW + l;
#pragma unroll
        for (int m = 0; m < 9; ++m) Jb[r][m] = p[(size_t)m * COL];
    }

    float d[3];

    // Warm-up: re-converge Q, discard log-norms. Prefetch t = s0+i+r+PF
    // (<= kacc+PF-1 <= 4035 < 4096, always in range).
    for (int i = 0; i < nwarm; i += PF) {
#pragma unroll
        for (int r = 0; r < PF; ++r) {
            lya_step(Jb[r], Q, d);
            const float* p = inp + (size_t)(s0 + i + r + PF) * ROW + l;
#pragma unroll
            for (int m = 0; m < 9; ++m) Jb[r][m] = p[(size_t)m * COL];
        }
    }

    // Accumulation: product-of-PF per chain, then one log2 per chain.
    for (int i = nwarm; i < nwarm + KSEG; i += PF) {
        float p0 = 1.f, p1 = 1.f, p2 = 1.f;
#pragma unroll
        for (int r = 0; r < PF; ++r) {
            lya_step(Jb[r], Q, d);
            p0 *= d[0]; p1 *= d[1]; p2 *= d[2];
            int tp = s0 + i + r + PF;
            if (tp > T_STEPS - 1) tp = T_STEPS - 1;   // tail: clamped redundant read
            const float* p = inp + (size_t)tp * ROW + l;
#pragma unroll
            for (int m = 0; m < 9; ++m) Jb[r][m] = p[(size_t)m * COL];
        }
        acc0 += __log2f(p0);
        acc1 += __log2f(p1);
        acc2 += __log2f(p2);
    }

    // log||b|| = 0.5*ln2*log2(d);  Lya = sum / (T*dt)
    const float scale = 0.5f * 0.69314718056f / (T_STEPS * 0.01f);
    atomicAdd(&out[0 * BATCH + l], acc0 * scale);
    atomicAdd(&out[1 * BATCH + l], acc1 * scale);
    atomicAdd(&out[2 * BATCH + l], acc2 * scale);
}

extern "C" void kernel_launch(void* const* d_in, const int* in_sizes, int n_in,
                              void* d_out, int out_size, void* d_ws, size_t ws_size,
                              hipStream_t stream) {
    const float* inp = (const float*)d_in[0];
    float* out = (float*)d_out;

    hipMemsetAsync(out, 0, (size_t)out_size * sizeof(float), stream);

    // NCHUNK chunks x BATCH threads = 131072 threads = 512 blocks of 256.
    dim3 grid(NCHUNK * BATCH / 256);
    dim3 block(256);
    lya_kernel<<<grid, block, 0, stream>>>(inp, out);
}

// Round 2
// 402.042 us; speedup vs baseline: 1.0294x; 1.0294x over previous
//
#include <hip/hip_runtime.h>

// Lyapunov spectrum via chunked QR scan with warm-up re-convergence.
// inp: (T=4096, 9, B=2048) fp32.  out: (3, B) fp32.
// R5: R3 structure (2 batches/thread, v2, NCHUNK=64, PF=4 ring, 1024 waves)
//     with WARM 32->16. Seam error e^{-0.31*16} ~ 7e-3 in Q -> ~4e-3 abs in
//     Lya (well inside tolerance). Warm-up HBM traffic halves: 453->377 MB
//     total (1.25x amplification instead of 1.5x).
// R4 post-mortem: scalar/2-waves-per-SIMD regressed +7.7us -> occupancy was
//     not the limiter; per-thread ILP + traffic are. Reverted to v2.

typedef float v2 __attribute__((ext_vector_type(2)));

constexpr int T_STEPS = 4096;
constexpr int BATCH   = 2048;
constexpr int NCHUNK  = 64;
constexpr int KSEG    = T_STEPS / NCHUNK;  // 64
constexpr int WARM    = 16;                // gap ~0.31/step -> e^-5 seam error
constexpr int PF      = 4;                 // prefetch ring depth (divides WARM and KSEG)

constexpr int ROWV2   = 9 * BATCH / 2;     // v2 elements per time step (9216)
constexpr int COLV2   = BATCH / 2;         // v2 elements per m column (1024)

__device__ __forceinline__ v2 rsq2(v2 x) {
    v2 r;
    r.x = __builtin_amdgcn_rsqf(x.x);
    r.y = __builtin_amdgcn_rsqf(x.y);
    return r;
}

__device__ __forceinline__ void lya_step(const v2 J[9], v2 Q[9], v2 d[3]) {
    // M = J * Q  (two independent 3x3 systems in the two v2 lanes)
    v2 M[9];
#pragma unroll
    for (int i = 0; i < 3; ++i) {
#pragma unroll
        for (int j = 0; j < 3; ++j) {
            M[i * 3 + j] = J[i * 3 + 0] * Q[0 * 3 + j]
                         + J[i * 3 + 1] * Q[1 * 3 + j]
                         + J[i * 3 + 2] * Q[2 * 3 + j];
        }
    }
    // Classical Gram-Schmidt (projections vs original cols), 1/d = rsq^2
    v2 b0x = M[0], b0y = M[3], b0z = M[6];
    v2 d00 = b0x * b0x + b0y * b0y + b0z * b0z;
    v2 r0 = rsq2(d00);
    v2 inv00 = r0 * r0;

    v2 x1x = M[1], x1y = M[4], x1z = M[7];
    v2 c01 = (b0x * x1x + b0y * x1y + b0z * x1z) * inv00;
    v2 b1x = x1x - c01 * b0x;
    v2 b1y = x1y - c01 * b0y;
    v2 b1z = x1z - c01 * b0z;
    v2 d11 = b1x * b1x + b1y * b1y + b1z * b1z;
    v2 r1 = rsq2(d11);
    v2 inv11 = r1 * r1;

    v2 x2x = M[2], x2y = M[5], x2z = M[8];
    v2 c02 = (b0x * x2x + b0y * x2y + b0z * x2z) * inv00;
    v2 c12 = (b1x * x2x + b1y * x2y + b1z * x2z) * inv11;
    v2 b2x = x2x - c02 * b0x - c12 * b1x;
    v2 b2y = x2y - c02 * b0y - c12 * b1y;
    v2 b2z = x2z - c02 * b0z - c12 * b1z;
    v2 d22 = b2x * b2x + b2y * b2y + b2z * b2z;
    v2 r2 = rsq2(d22);

    Q[0] = b0x * r0; Q[3] = b0y * r0; Q[6] = b0z * r0;
    Q[1] = b1x * r1; Q[4] = b1y * r1; Q[7] = b1z * r1;
    Q[2] = b2x * r2; Q[5] = b2y * r2; Q[8] = b2z * r2;
    d[0] = d00; d[1] = d11; d[2] = d22;
}

__global__ __launch_bounds__(256) void lya_kernel(const float* __restrict__ inp,
                                                  float* __restrict__ out) {
    const int tid   = blockIdx.x * 256 + threadIdx.x;
    const int l     = tid & (COLV2 - 1);   // thread-in-chunk, handles batches 2l, 2l+1
    const int chunk = tid >> 10;           // block-uniform (1024 threads/chunk)
    const int kacc  = chunk * KSEG;
    const int s0    = (kacc >= WARM) ? (kacc - WARM) : 0;
    const int nwarm = kacc - s0;           // 0 (chunk 0) or WARM

    const v2* __restrict__ base = (const v2*)inp;

    v2 one = {1.f, 1.f}, zero = {0.f, 0.f};
    v2 Q[9] = {one, zero, zero,
               zero, one, zero,
               zero, zero, one};
    v2 acc0 = zero, acc1 = zero, acc2 = zero;

    // Preload PF-deep ring: steps s0 .. s0+PF-1 (s0+PF-1 <= 4016+3 < 4096).
    v2 Jb[PF][9];
#pragma unroll
    for (int r = 0; r < PF; ++r) {
        const v2* p = base + (size_t)(s0 + r) * ROWV2 + l;
#pragma unroll
        for (int m = 0; m < 9; ++m) Jb[r][m] = p[(size_t)m * COLV2];
    }

    v2 d[3];

    // Warm-up: re-converge Q, discard log-norms. Prefetch t = s0+i+r+PF
    // (<= kacc+PF-1 <= 4035 < 4096, always in range).
    for (int i = 0; i < nwarm; i += PF) {
#pragma unroll
        for (int r = 0; r < PF; ++r) {
            lya_step(Jb[r], Q, d);
            const v2* p = base + (size_t)(s0 + i + r + PF) * ROWV2 + l;
#pragma unroll
            for (int m = 0; m < 9; ++m) Jb[r][m] = p[(size_t)m * COLV2];
        }
    }

    // Accumulation: product-of-PF per chain, then one log2 per chain component.
    for (int i = nwarm; i < nwarm + KSEG; i += PF) {
        v2 p0 = one, p1 = one, p2 = one;
#pragma unroll
        for (int r = 0; r < PF; ++r) {
            lya_step(Jb[r], Q, d);
            p0 *= d[0]; p1 *= d[1]; p2 *= d[2];
            int tp = s0 + i + r + PF;
            if (tp > T_STEPS - 1) tp = T_STEPS - 1;   // tail: clamped redundant read
            const v2* p = base + (size_t)tp * ROWV2 + l;
#pragma unroll
            for (int m = 0; m < 9; ++m) Jb[r][m] = p[(size_t)m * COLV2];
        }
        acc0.x += __log2f(p0.x); acc0.y += __log2f(p0.y);
        acc1.x += __log2f(p1.x); acc1.y += __log2f(p1.y);
        acc2.x += __log2f(p2.x); acc2.y += __log2f(p2.y);
    }

    // log||b|| = 0.5*ln2*log2(d);  Lya = sum / (T*dt)
    const float scale = 0.5f * 0.69314718056f / (T_STEPS * 0.01f);
    const int b0 = l * 2;
    atomicAdd(&out[0 * BATCH + b0],     acc0.x * scale);
    atomicAdd(&out[0 * BATCH + b0 + 1], acc0.y * scale);
    atomicAdd(&out[1 * BATCH + b0],     acc1.x * scale);
    atomicAdd(&out[1 * BATCH + b0 + 1], acc1.y * scale);
    atomicAdd(&out[2 * BATCH + b0],     acc2.x * scale);
    atomicAdd(&out[2 * BATCH + b0 + 1], acc2.y * scale);
}

extern "C" void kernel_launch(void* const* d_in, const int* in_sizes, int n_in,
                              void* d_out, int out_size, void* d_ws, size_t ws_size,
                              hipStream_t stream) {
    const float* inp = (const float*)d_in[0];
    float* out = (float*)d_out;

    hipMemsetAsync(out, 0, (size_t)out_size * sizeof(float), stream);

    // NCHUNK chunks x (BATCH/2) threads = 65536 threads = 256 blocks of 256.
    dim3 grid(NCHUNK * COLV2 / 256);
    dim3 block(256);
    lya_kernel<<<grid, block, 0, stream>>>(inp, out);
}

// Round 3
// 399.522 us; speedup vs baseline: 1.0359x; 1.0063x over previous
//
#include <hip/hip_runtime.h>

// Lyapunov spectrum via chunked QR scan with warm-up re-convergence.
// inp: (T=4096, 9, B=2048) fp32.  out: (3, B) fp32.
// R6: v2 structure (2 batches/thread, NCHUNK=64, 1024 waves = 1/SIMD) with
//     WARM 16->8 (seam err O(eps^2), eps=e^{-2.5}: ~0.01 abs, 50x margin) and
//     PF 4->8 (ring 144 VGPR; occupancy-free at 1 wave/SIMD up to ~512 VGPR;
//     doubles load->use distance to ~2400 cyc vs ~900 cyc HBM latency).
// R4 post-mortem: 2 waves/SIMD via scalar loads regressed (+7.7us) -> width
//     + per-thread ILP beat occupancy. R5: WARM 32->16 gave -4.2us (partial
//     of predicted -12 -> kernel is latency-elevated above its BW floor).

typedef float v2 __attribute__((ext_vector_type(2)));

constexpr int T_STEPS = 4096;
constexpr int BATCH   = 2048;
constexpr int NCHUNK  = 64;
constexpr int KSEG    = T_STEPS / NCHUNK;  // 64
constexpr int WARM    = 8;                 // gap ~0.31/step; err 2nd-order in e^-2.5
constexpr int PF      = 8;                 // prefetch ring depth (divides WARM and KSEG)

constexpr int ROWV2   = 9 * BATCH / 2;     // v2 elements per time step (9216)
constexpr int COLV2   = BATCH / 2;         // v2 elements per m column (1024)

__device__ __forceinline__ v2 rsq2(v2 x) {
    v2 r;
    r.x = __builtin_amdgcn_rsqf(x.x);
    r.y = __builtin_amdgcn_rsqf(x.y);
    return r;
}

__device__ __forceinline__ void lya_step(const v2 J[9], v2 Q[9], v2 d[3]) {
    // M = J * Q  (two independent 3x3 systems in the two v2 lanes)
    v2 M[9];
#pragma unroll
    for (int i = 0; i < 3; ++i) {
#pragma unroll
        for (int j = 0; j < 3; ++j) {
            M[i * 3 + j] = J[i * 3 + 0] * Q[0 * 3 + j]
                         + J[i * 3 + 1] * Q[1 * 3 + j]
                         + J[i * 3 + 2] * Q[2 * 3 + j];
        }
    }
    // Classical Gram-Schmidt (projections vs original cols), 1/d = rsq^2
    v2 b0x = M[0], b0y = M[3], b0z = M[6];
    v2 d00 = b0x * b0x + b0y * b0y + b0z * b0z;
    v2 r0 = rsq2(d00);
    v2 inv00 = r0 * r0;

    v2 x1x = M[1], x1y = M[4], x1z = M[7];
    v2 c01 = (b0x * x1x + b0y * x1y + b0z * x1z) * inv00;
    v2 b1x = x1x - c01 * b0x;
    v2 b1y = x1y - c01 * b0y;
    v2 b1z = x1z - c01 * b0z;
    v2 d11 = b1x * b1x + b1y * b1y + b1z * b1z;
    v2 r1 = rsq2(d11);
    v2 inv11 = r1 * r1;

    v2 x2x = M[2], x2y = M[5], x2z = M[8];
    v2 c02 = (b0x * x2x + b0y * x2y + b0z * x2z) * inv00;
    v2 c12 = (b1x * x2x + b1y * x2y + b1z * x2z) * inv11;
    v2 b2x = x2x - c02 * b0x - c12 * b1x;
    v2 b2y = x2y - c02 * b0y - c12 * b1y;
    v2 b2z = x2z - c02 * b0z - c12 * b1z;
    v2 d22 = b2x * b2x + b2y * b2y + b2z * b2z;
    v2 r2 = rsq2(d22);

    Q[0] = b0x * r0; Q[3] = b0y * r0; Q[6] = b0z * r0;
    Q[1] = b1x * r1; Q[4] = b1y * r1; Q[7] = b1z * r1;
    Q[2] = b2x * r2; Q[5] = b2y * r2; Q[8] = b2z * r2;
    d[0] = d00; d[1] = d11; d[2] = d22;
}

__global__ __launch_bounds__(256) void lya_kernel(const float* __restrict__ inp,
                                                  float* __restrict__ out) {
    const int tid   = blockIdx.x * 256 + threadIdx.x;
    const int l     = tid & (COLV2 - 1);   // thread-in-chunk, handles batches 2l, 2l+1
    const int chunk = tid >> 10;           // block-uniform (1024 threads/chunk)
    const int kacc  = chunk * KSEG;
    const int s0    = (kacc >= WARM) ? (kacc - WARM) : 0;
    const int nwarm = kacc - s0;           // 0 (chunk 0) or WARM

    const v2* __restrict__ base = (const v2*)inp;

    v2 one = {1.f, 1.f}, zero = {0.f, 0.f};
    v2 Q[9] = {one, zero, zero,
               zero, one, zero,
               zero, zero, one};
    v2 acc0 = zero, acc1 = zero, acc2 = zero;

    // Preload PF-deep ring: steps s0 .. s0+PF-1 (max s0 = 4024, +7 = 4031 < 4096).
    v2 Jb[PF][9];
#pragma unroll
    for (int r = 0; r < PF; ++r) {
        const v2* p = base + (size_t)(s0 + r) * ROWV2 + l;
#pragma unroll
        for (int m = 0; m < 9; ++m) Jb[r][m] = p[(size_t)m * COLV2];
    }

    v2 d[3];

    // Warm-up: re-converge Q, discard log-norms. Prefetch t = s0+i+r+PF
    // (<= kacc+PF-1 <= 4039 < 4096, always in range).
    for (int i = 0; i < nwarm; i += PF) {
#pragma unroll
        for (int r = 0; r < PF; ++r) {
            lya_step(Jb[r], Q, d);
            const v2* p = base + (size_t)(s0 + i + r + PF) * ROWV2 + l;
#pragma unroll
            for (int m = 0; m < 9; ++m) Jb[r][m] = p[(size_t)m * COLV2];
        }
    }

    // Accumulation: product-of-PF per chain, then one log2 per chain component.
    for (int i = nwarm; i < nwarm + KSEG; i += PF) {
        v2 p0 = one, p1 = one, p2 = one;
#pragma unroll
        for (int r = 0; r < PF; ++r) {
            lya_step(Jb[r], Q, d);
            p0 *= d[0]; p1 *= d[1]; p2 *= d[2];
            int tp = s0 + i + r + PF;
            if (tp > T_STEPS - 1) tp = T_STEPS - 1;   // tail: clamped redundant read
            const v2* p = base + (size_t)tp * ROWV2 + l;
#pragma unroll
            for (int m = 0; m < 9; ++m) Jb[r][m] = p[(size_t)m * COLV2];
        }
        acc0.x += __log2f(p0.x); acc0.y += __log2f(p0.y);
        acc1.x += __log2f(p1.x); acc1.y += __log2f(p1.y);
        acc2.x += __log2f(p2.x); acc2.y += __log2f(p2.y);
    }

    // log||b|| = 0.5*ln2*log2(d);  Lya = sum / (T*dt)
    const float scale = 0.5f * 0.69314718056f / (T_STEPS * 0.01f);
    const int b0 = l * 2;
    atomicAdd(&out[0 * BATCH + b0],     acc0.x * scale);
    atomicAdd(&out[0 * BATCH + b0 + 1], acc0.y * scale);
    atomicAdd(&out[1 * BATCH + b0],     acc1.x * scale);
    atomicAdd(&out[1 * BATCH + b0 + 1], acc1.y * scale);
    atomicAdd(&out[2 * BATCH + b0],     acc2.x * scale);
    atomicAdd(&out[2 * BATCH + b0 + 1], acc2.y * scale);
}

extern "C" void kernel_launch(void* const* d_in, const int* in_sizes, int n_in,
                              void* d_out, int out_size, void* d_ws, size_t ws_size,
                              hipStream_t stream) {
    const float* inp = (const float*)d_in[0];
    float* out = (float*)d_out;

    hipMemsetAsync(out, 0, (size_t)out_size * sizeof(float), stream);

    // NCHUNK chunks x (BATCH/2) threads = 65536 threads = 256 blocks of 256.
    dim3 grid(NCHUNK * COLV2 / 256);
    dim3 block(256);
    lya_kernel<<<grid, block, 0, stream>>>(inp, out);
}